// Round 3
// baseline (9261.920 us; speedup 1.0000x reference)
//
#include <hip/hip_runtime.h>
#include <hip/hip_bf16.h>
#include <math.h>

// Model dims
#define Tt 256
#define TT 768      // 3*t
#define CC 768
#define HH 12
#define DD 64
#define MC 438
#define VV 512
#define FCC 3072

typedef __hip_bfloat16 bf16;
typedef __bf16 bf16x8 __attribute__((ext_vector_type(8)));
typedef float f32x4 __attribute__((ext_vector_type(4)));

__device__ __forceinline__ float b2f(bf16 v) { return __bfloat162float(v); }
__device__ __forceinline__ bf16 f2b(float v) { return __float2bfloat16(v); }

// load 8 consecutive f32 and convert to bf16x8 (for MFMA fragments)
__device__ __forceinline__ bf16x8 ld8f(const float* __restrict__ p) {
    f32x4 a = *(const f32x4*)p;
    f32x4 b = *(const f32x4*)(p + 4);
    bf16x8 r;
    r[0] = (__bf16)a[0]; r[1] = (__bf16)a[1]; r[2] = (__bf16)a[2]; r[3] = (__bf16)a[3];
    r[4] = (__bf16)b[0]; r[5] = (__bf16)b[1]; r[6] = (__bf16)b[2]; r[7] = (__bf16)b[3];
    return r;
}

// ---------------------------------------------------------------------------
// Embed: x[b,i,:] = (i<t ? cond@cond_w^T+cond_b : tok_gather) + pos_emb
// All inputs float32. Output fp32 residual stream.
// ---------------------------------------------------------------------------
__global__ __launch_bounds__(256) void embed_kernel(
    const int* __restrict__ idx_up, const int* __restrict__ idx_down,
    const float* __restrict__ cond, const float* __restrict__ tok_up,
    const float* __restrict__ tok_down, const float* __restrict__ pos,
    const float* __restrict__ cond_w, const float* __restrict__ cond_b,
    float* __restrict__ x)
{
    int row = blockIdx.x;          // b*768 + i
    int b = row / TT, i = row - b * TT;
    int tid = threadIdx.x;
    for (int c = tid; c < CC; c += 256) {
        float v;
        if (i < Tt) {
            const float* crow = cond + (size_t)(b * Tt + i) * MC;
            const float* wrow = cond_w + (size_t)c * MC;
            float acc = 0.f;
            for (int m = 0; m < MC; m++) acc += crow[m] * wrow[m];
            v = acc + cond_b[c];
        } else if (i < 2 * Tt) {
            int ix = idx_up[b * Tt + (i - Tt)];
            v = tok_up[(size_t)ix * CC + c];
        } else {
            int ix = idx_down[b * Tt + (i - 2 * Tt)];
            v = tok_down[(size_t)ix * CC + c];
        }
        x[(size_t)row * CC + c] = v + pos[(size_t)i * CC + c];
    }
}

// ---------------------------------------------------------------------------
// LayerNorm over C=768: fp32 in, bf16 out. w,b are f32.
// ---------------------------------------------------------------------------
__global__ __launch_bounds__(256) void ln_kernel(
    const float* __restrict__ x, const float* __restrict__ w,
    const float* __restrict__ b, bf16* __restrict__ out)
{
    __shared__ float red[256];
    int row = blockIdx.x, tid = threadIdx.x;
    const float* xr = x + (size_t)row * CC;
    float v0 = xr[tid], v1 = xr[tid + 256], v2 = xr[tid + 512];
    red[tid] = v0 + v1 + v2;
    __syncthreads();
    for (int st = 128; st > 0; st >>= 1) {
        if (tid < st) red[tid] += red[tid + st];
        __syncthreads();
    }
    float mu = red[0] * (1.0f / 768.0f);
    __syncthreads();
    float d0 = v0 - mu, d1 = v1 - mu, d2 = v2 - mu;
    red[tid] = d0 * d0 + d1 * d1 + d2 * d2;
    __syncthreads();
    for (int st = 128; st > 0; st >>= 1) {
        if (tid < st) red[tid] += red[tid + st];
        __syncthreads();
    }
    float rstd = rsqrtf(red[0] * (1.0f / 768.0f) + 1e-5f);
    bf16* orow = out + (size_t)row * CC;
    orow[tid]       = f2b(d0 * rstd * w[tid]       + b[tid]);
    orow[tid + 256] = f2b(d1 * rstd * w[tid + 256] + b[tid + 256]);
    orow[tid + 512] = f2b(d2 * rstd * w[tid + 512] + b[tid + 512]);
}

// ---------------------------------------------------------------------------
// GEMM: out[m,n] = sum_k A[m,k]*W[n,k] (+bias)(+gelu)(+residual), MFMA bf16
// A: bf16 (our own buffers). W,bias: float32 (harness inputs), converted
// to bf16 fragments in-register. Block=256thr=4 waves; tile 64Mx64N.
// ---------------------------------------------------------------------------
#define GF_BIAS 1
#define GF_GELU 2
#define GF_RES  4
#define GF_OUTB 8
#define GF_ROWMAP 16

template <int F>
__global__ __launch_bounds__(256) void gemm_k(
    const bf16* __restrict__ A, const float* __restrict__ W,
    const float* __restrict__ bias, float* __restrict__ outf,
    bf16* __restrict__ outb, int M, int N, int K, int seg)
{
    int lane = threadIdx.x & 63;
    int wave = threadIdx.x >> 6;
    int q = lane >> 4, r = lane & 15;
    int m0 = blockIdx.y * 64 + wave * 16;
    int n0 = blockIdx.x * 64;

    int am = m0 + r;
    if (F & GF_ROWMAP) am = (am >> 8) * TT + seg * Tt + (am & 255);
    const bf16* arow   = A + (size_t)am * K + q * 8;
    const float* wbase = W + (size_t)(n0 + r) * K + q * 8;

    f32x4 acc[4] = {{0,0,0,0},{0,0,0,0},{0,0,0,0},{0,0,0,0}};
    for (int k0 = 0; k0 < K; k0 += 32) {
        bf16x8 a  = *(const bf16x8*)(arow + k0);
        bf16x8 b0 = ld8f(wbase + k0);
        bf16x8 b1 = ld8f(wbase + (size_t)16 * K + k0);
        bf16x8 b2 = ld8f(wbase + (size_t)32 * K + k0);
        bf16x8 b3 = ld8f(wbase + (size_t)48 * K + k0);
        acc[0] = __builtin_amdgcn_mfma_f32_16x16x32_bf16(a, b0, acc[0], 0, 0, 0);
        acc[1] = __builtin_amdgcn_mfma_f32_16x16x32_bf16(a, b1, acc[1], 0, 0, 0);
        acc[2] = __builtin_amdgcn_mfma_f32_16x16x32_bf16(a, b2, acc[2], 0, 0, 0);
        acc[3] = __builtin_amdgcn_mfma_f32_16x16x32_bf16(a, b3, acc[3], 0, 0, 0);
    }
#pragma unroll
    for (int nt = 0; nt < 4; nt++) {
#pragma unroll
        for (int i = 0; i < 4; i++) {
            int row = m0 + q * 4 + i;
            int col = n0 + nt * 16 + r;
            float v = acc[nt][i];
            if (F & GF_BIAS) v += bias[col];
            if (F & GF_GELU) v = 0.5f * v * (1.0f + erff(v * 0.70710678118654752f));
            size_t oi = (size_t)row * N + col;
            if (F & GF_RES) v += outf[oi];
            if (F & GF_OUTB) outb[oi] = f2b(v);
            else             outf[oi] = v;
        }
    }
}

// ---------------------------------------------------------------------------
// Attention: one block per (b,h,query i). qkv bf16 [B*T, 2304]:
//   q = qkv[(b*T+j)*2304 + h*64 + d], k at +768, v at +1536
// mask: key j allowed iff (j%t) <= (i%t)
// ---------------------------------------------------------------------------
__global__ __launch_bounds__(256) void attn_kernel(
    const bf16* __restrict__ qkv, bf16* __restrict__ yout)
{
    __shared__ float qs[DD];
    __shared__ float sc[TT];
    __shared__ float red[256];

    int bid = blockIdx.x;
    int i = bid % TT;
    int bh = bid / TT;
    int h = bh % HH, b = bh / HH;
    int p = i & (Tt - 1);
    int tid = threadIdx.x;

    const bf16* qrow = qkv + (size_t)(b * TT + i) * 2304 + h * DD;
    if (tid < DD) qs[tid] = b2f(qrow[tid]);
    __syncthreads();

    float ls[3];
    float lmax = -INFINITY;
#pragma unroll
    for (int c = 0; c < 3; c++) {
        int j = tid + c * 256;
        float s = -INFINITY;
        if ((j & (Tt - 1)) <= p) {
            const bf16* krow = qkv + (size_t)(b * TT + j) * 2304 + CC + h * DD;
            float acc = 0.f;
#pragma unroll
            for (int d = 0; d < DD; d++) acc += qs[d] * b2f(krow[d]);
            s = acc * 0.125f;  // 1/sqrt(64)
        }
        ls[c] = s;
        lmax = fmaxf(lmax, s);
    }
    red[tid] = lmax;
    __syncthreads();
    for (int st = 128; st > 0; st >>= 1) {
        if (tid < st) red[tid] = fmaxf(red[tid], red[tid + st]);
        __syncthreads();
    }
    float mx = red[0];
    __syncthreads();
    float lsum = 0.f;
#pragma unroll
    for (int c = 0; c < 3; c++) {
        float e = __expf(ls[c] - mx);  // masked: exp(-inf)=0
        sc[tid + c * 256] = e;
        lsum += e;
    }
    red[tid] = lsum;
    __syncthreads();
    for (int st = 128; st > 0; st >>= 1) {
        if (tid < st) red[tid] += red[tid + st];
        __syncthreads();
    }
    float inv = 1.0f / red[0];

    if (tid < DD) {
        const bf16* vbase = qkv + (size_t)(b * TT) * 2304 + 2 * CC + h * DD + tid;
        float acc = 0.f;
        for (int j = 0; j < TT; j++) acc += sc[j] * b2f(vbase[(size_t)j * 2304]);
        yout[(size_t)(b * TT + i) * CC + h * DD + tid] = f2b(acc * inv);
    }
}

// ---------------------------------------------------------------------------
extern "C" void kernel_launch(void* const* d_in, const int* in_sizes, int n_in,
                              void* d_out, int out_size, void* d_ws, size_t ws_size,
                              hipStream_t stream)
{
    const int* idx_up     = (const int*)d_in[0];
    const int* idx_down   = (const int*)d_in[1];
    const float* cond     = (const float*)d_in[2];
    const float* tok_up   = (const float*)d_in[3];
    const float* tok_down = (const float*)d_in[4];
    const float* pos_emb  = (const float*)d_in[5];
    const float* cond_w   = (const float*)d_in[6];
    const float* cond_b   = (const float*)d_in[7];
    const float* lnf_w    = (const float*)d_in[8];
    const float* lnf_b    = (const float*)d_in[9];
    const float* head_up_w   = (const float*)d_in[10];
    const float* head_down_w = (const float*)d_in[11];
    // per-stack params: ln1, ln2, qkv_w, qkv_b, proj_w, proj_b, fc1_w, fc1_b, fc2_w, fc2_b
    const float* P[2][10];
    for (int s = 0; s < 2; s++)
        for (int j = 0; j < 10; j++)
            P[s][j] = (const float*)d_in[12 + s * 10 + j];

    const int Mrows = 2 * TT;  // 1536
    // Workspace layout (aliased lifetimes, ~16.5 MiB):
    //   x    fp32 [1536,768]                           4,718,592 B
    //   bufA bf16 union{qkv[1536,2304], g[1536,3072]}  9,437,184 B
    //   bufB bf16 union{h[1536,768], att[1536,768]}    2,359,296 B
    char* wsp = (char*)d_ws;
    float* x   = (float*)wsp;
    bf16* bufA = (bf16*)(wsp + 4718592);
    bf16* bufB = (bf16*)(wsp + 4718592 + 9437184);
    bf16* qkv = bufA;   // dead after attn
    bf16* g   = bufA;   // written by fc1 (after attn reads done)
    bf16* h   = bufB;   // ln out; consumed by next GEMM
    bf16* att = bufB;   // attn out (h dead), read by proj, then ln2 overwrites
    float* outf = (float*)d_out;

    embed_kernel<<<Mrows, 256, 0, stream>>>(idx_up, idx_down, cond, tok_up,
                                            tok_down, pos_emb, cond_w, cond_b, x);

    for (int l = 0; l < 12; l++) {
        int s = l / 6, ll = l % 6;
        const float* ln1    = P[s][0] + (size_t)ll * 2 * CC;
        const float* ln2    = P[s][1] + (size_t)ll * 2 * CC;
        const float* qkv_w  = P[s][2] + (size_t)ll * 3 * CC * CC;
        const float* qkv_b  = P[s][3] + (size_t)ll * 3 * CC;
        const float* proj_w = P[s][4] + (size_t)ll * CC * CC;
        const float* proj_b = P[s][5] + (size_t)ll * CC;
        const float* fc1_w  = P[s][6] + (size_t)ll * 4 * CC * CC;
        const float* fc1_b  = P[s][7] + (size_t)ll * 4 * CC;
        const float* fc2_w  = P[s][8] + (size_t)ll * 4 * CC * CC;
        const float* fc2_b  = P[s][9] + (size_t)ll * CC;

        ln_kernel<<<Mrows, 256, 0, stream>>>(x, ln1, ln1 + CC, h);
        gemm_k<GF_BIAS | GF_OUTB><<<dim3(3 * CC / 64, Mrows / 64), 256, 0, stream>>>(
            h, qkv_w, qkv_b, nullptr, qkv, Mrows, 3 * CC, CC, 0);
        attn_kernel<<<2 * HH * TT, 256, 0, stream>>>(qkv, att);
        gemm_k<GF_BIAS | GF_RES><<<dim3(CC / 64, Mrows / 64), 256, 0, stream>>>(
            att, proj_w, proj_b, x, nullptr, Mrows, CC, CC, 0);
        ln_kernel<<<Mrows, 256, 0, stream>>>(x, ln2, ln2 + CC, h);
        gemm_k<GF_BIAS | GF_GELU | GF_OUTB><<<dim3(FCC / 64, Mrows / 64), 256, 0, stream>>>(
            h, fc1_w, fc1_b, nullptr, g, Mrows, FCC, CC, 0);
        gemm_k<GF_BIAS | GF_RES><<<dim3(CC / 64, Mrows / 64), 256, 0, stream>>>(
            g, fc2_w, fc2_b, x, nullptr, Mrows, CC, FCC, 0);
    }

    ln_kernel<<<Mrows, 256, 0, stream>>>(x, lnf_w, lnf_b, h);
    // logits_up: A rows b*T + t + i ; logits_down: A rows b*T + 2t + i (f32 out)
    gemm_k<GF_ROWMAP><<<dim3(VV / 64, 2 * Tt / 64), 256, 0, stream>>>(
        h, head_up_w, nullptr, outf, nullptr, 2 * Tt, VV, CC, 1);
    gemm_k<GF_ROWMAP><<<dim3(VV / 64, 2 * Tt / 64), 256, 0, stream>>>(
        h, head_down_w, nullptr, outf + (size_t)2 * Tt * VV, nullptr, 2 * Tt, VV, CC, 2);
}

// Round 4
// 3918.291 us; speedup vs baseline: 2.3638x; 2.3638x over previous
//
#include <hip/hip_runtime.h>
#include <hip/hip_bf16.h>
#include <math.h>

// Model dims
#define Tt 256
#define TT 768      // 3*t
#define CC 768
#define HH 12
#define DD 64
#define MC 438
#define VV 512
#define FCC 3072

typedef __hip_bfloat16 bf16;
typedef __bf16 bf16x4 __attribute__((ext_vector_type(4)));
typedef __bf16 bf16x8 __attribute__((ext_vector_type(8)));
typedef float f32x4 __attribute__((ext_vector_type(4)));

__device__ __forceinline__ float b2f(bf16 v) { return __bfloat162float(v); }
__device__ __forceinline__ bf16 f2b(float v) { return __float2bfloat16(v); }

// ---------------------------------------------------------------------------
// Embed: x[b,i,:] = (i<t ? cond@cond_w^T+cond_b : tok_gather) + pos_emb
// ---------------------------------------------------------------------------
__global__ __launch_bounds__(256) void embed_kernel(
    const int* __restrict__ idx_up, const int* __restrict__ idx_down,
    const float* __restrict__ cond, const float* __restrict__ tok_up,
    const float* __restrict__ tok_down, const float* __restrict__ pos,
    const float* __restrict__ cond_w, const float* __restrict__ cond_b,
    float* __restrict__ x)
{
    int row = blockIdx.x;          // b*768 + i
    int b = row / TT, i = row - b * TT;
    int tid = threadIdx.x;
    for (int c = tid; c < CC; c += 256) {
        float v;
        if (i < Tt) {
            const float* crow = cond + (size_t)(b * Tt + i) * MC;
            const float* wrow = cond_w + (size_t)c * MC;
            float acc = 0.f;
            for (int m = 0; m < MC; m++) acc += crow[m] * wrow[m];
            v = acc + cond_b[c];
        } else if (i < 2 * Tt) {
            int ix = idx_up[b * Tt + (i - Tt)];
            v = tok_up[(size_t)ix * CC + c];
        } else {
            int ix = idx_down[b * Tt + (i - 2 * Tt)];
            v = tok_down[(size_t)ix * CC + c];
        }
        x[(size_t)row * CC + c] = v + pos[(size_t)i * CC + c];
    }
}

// ---------------------------------------------------------------------------
// LayerNorm over C=768: fp32 in, bf16 out. w,b f32.
// ---------------------------------------------------------------------------
__global__ __launch_bounds__(256) void ln_kernel(
    const float* __restrict__ x, const float* __restrict__ w,
    const float* __restrict__ b, bf16* __restrict__ out)
{
    __shared__ float red[256];
    int row = blockIdx.x, tid = threadIdx.x;
    const float* xr = x + (size_t)row * CC;
    float v0 = xr[tid], v1 = xr[tid + 256], v2 = xr[tid + 512];
    red[tid] = v0 + v1 + v2;
    __syncthreads();
    for (int st = 128; st > 0; st >>= 1) {
        if (tid < st) red[tid] += red[tid + st];
        __syncthreads();
    }
    float mu = red[0] * (1.0f / 768.0f);
    __syncthreads();
    float d0 = v0 - mu, d1 = v1 - mu, d2 = v2 - mu;
    red[tid] = d0 * d0 + d1 * d1 + d2 * d2;
    __syncthreads();
    for (int st = 128; st > 0; st >>= 1) {
        if (tid < st) red[tid] += red[tid + st];
        __syncthreads();
    }
    float rstd = rsqrtf(red[0] * (1.0f / 768.0f) + 1e-5f);
    bf16* orow = out + (size_t)row * CC;
    orow[tid]       = f2b(d0 * rstd * w[tid]       + b[tid]);
    orow[tid + 256] = f2b(d1 * rstd * w[tid + 256] + b[tid + 256]);
    orow[tid + 512] = f2b(d2 * rstd * w[tid + 512] + b[tid + 512]);
}

// ---------------------------------------------------------------------------
// GEMM 128x128 tile, LDS-staged: out[m,n] = sum_k A[m,k]*W[n,k] (+flags)
// A bf16 [M,K]; W f32 [N,K] converted to bf16 during staging.
// 256 thr = 4 waves (2x2 of 64x64); BK=32; 2 barriers/iter.
// ---------------------------------------------------------------------------
#define GF_BIAS 1
#define GF_GELU 2
#define GF_RES  4
#define GF_OUTB 8
#define GF_ROWMAP 16

template <int F>
__global__ __launch_bounds__(256) void gemm2(
    const bf16* __restrict__ A, const float* __restrict__ W,
    const float* __restrict__ bias, float* __restrict__ outf,
    bf16* __restrict__ outb, int M, int N, int K, int seg)
{
    __shared__ __align__(16) __bf16 As[128 * 32];   // row stride 32 elem
    __shared__ __align__(16) __bf16 Ws[128 * 40];   // row stride 40 elem (bank spread)

    int tid = threadIdx.x;
    int wv = tid >> 6, lane = tid & 63, quad = lane >> 4, r = lane & 15;
    int m0 = blockIdx.y * 128, n0 = blockIdx.x * 128;
    int mw = (wv & 1) * 64, nw = (wv >> 1) * 64;

    // A staging: 512 slots of 8 bf16; slot idx -> row=idx>>2, colelem=(idx&3)*8
    int idx0 = tid, idx1 = tid + 256;
    int am0 = m0 + (idx0 >> 2), am1 = m0 + (idx1 >> 2);
    if (F & GF_ROWMAP) {
        am0 = (am0 >> 8) * TT + seg * Tt + (am0 & 255);
        am1 = (am1 >> 8) * TT + seg * Tt + (am1 & 255);
    }
    const bf16* ap0 = A + (size_t)am0 * K + (idx0 & 3) * 8;
    const bf16* ap1 = A + (size_t)am1 * K + (idx1 & 3) * 8;
    // W staging: row wr=tid>>1, half wh=tid&1 -> 16 f32
    int wr = tid >> 1, wh = tid & 1;
    const float* wp = W + (size_t)(n0 + wr) * K + wh * 16;

    f32x4 acc[16];
#pragma unroll
    for (int z = 0; z < 16; z++) acc[z] = (f32x4){0.f, 0.f, 0.f, 0.f};

    for (int k0 = 0; k0 < K; k0 += 32) {
        *(bf16x8*)(As + idx0 * 8) = *(const bf16x8*)(ap0 + k0);
        *(bf16x8*)(As + idx1 * 8) = *(const bf16x8*)(ap1 + k0);
        f32x4 w0 = *(const f32x4*)(wp + k0);
        f32x4 w1 = *(const f32x4*)(wp + k0 + 4);
        f32x4 w2 = *(const f32x4*)(wp + k0 + 8);
        f32x4 w3 = *(const f32x4*)(wp + k0 + 12);
        bf16x8 wlo, whi;
        wlo[0] = (__bf16)w0[0]; wlo[1] = (__bf16)w0[1]; wlo[2] = (__bf16)w0[2]; wlo[3] = (__bf16)w0[3];
        wlo[4] = (__bf16)w1[0]; wlo[5] = (__bf16)w1[1]; wlo[6] = (__bf16)w1[2]; wlo[7] = (__bf16)w1[3];
        whi[0] = (__bf16)w2[0]; whi[1] = (__bf16)w2[1]; whi[2] = (__bf16)w2[2]; whi[3] = (__bf16)w2[3];
        whi[4] = (__bf16)w3[0]; whi[5] = (__bf16)w3[1]; whi[6] = (__bf16)w3[2]; whi[7] = (__bf16)w3[3];
        *(bf16x8*)(Ws + wr * 40 + wh * 16) = wlo;
        *(bf16x8*)(Ws + wr * 40 + wh * 16 + 8) = whi;
        __syncthreads();

        bf16x8 af[4], bf[4];
#pragma unroll
        for (int mi = 0; mi < 4; mi++)
            af[mi] = *(const bf16x8*)(As + (mw + mi * 16 + r) * 32 + quad * 8);
#pragma unroll
        for (int ni = 0; ni < 4; ni++)
            bf[ni] = *(const bf16x8*)(Ws + (nw + ni * 16 + r) * 40 + quad * 8);
#pragma unroll
        for (int mi = 0; mi < 4; mi++)
#pragma unroll
            for (int ni = 0; ni < 4; ni++)
                acc[mi * 4 + ni] = __builtin_amdgcn_mfma_f32_16x16x32_bf16(
                    af[mi], bf[ni], acc[mi * 4 + ni], 0, 0, 0);
        __syncthreads();
    }

#pragma unroll
    for (int mi = 0; mi < 4; mi++) {
        int row = m0 + mw + mi * 16 + quad * 4;
#pragma unroll
        for (int ni = 0; ni < 4; ni++) {
            int col = n0 + nw + ni * 16 + r;
            float bv = (F & GF_BIAS) ? bias[col] : 0.f;
            f32x4 v4 = acc[mi * 4 + ni];
#pragma unroll
            for (int i = 0; i < 4; i++) {
                float v = v4[i] + bv;
                if (F & GF_GELU) v = 0.5f * v * (1.0f + erff(v * 0.70710678118654752f));
                size_t oi = (size_t)(row + i) * N + col;
                if (F & GF_RES) v += outf[oi];
                if (F & GF_OUTB) outb[oi] = f2b(v);
                else             outf[oi] = v;
            }
        }
    }
}

// ---------------------------------------------------------------------------
// Flash attention, MFMA. Block = (b, h, 64-query tile); 4 waves x 16 queries.
// qkv bf16 [B*T, 2304]: q at h*64, k at 768+h*64, v at 1536+h*64.
// mask: (j%256) <= (i%256); tiles with jm<p0 full, jm==p0 diagonal, jm>p0 skip.
// ---------------------------------------------------------------------------
__global__ __launch_bounds__(256) void attn_mfma(
    const bf16* __restrict__ qkv, bf16* __restrict__ yout)
{
    __shared__ __align__(16) __bf16 Pl[64 * 72];  // P[q][j], stride 72 (16B-aligned rows)
    __shared__ __align__(16) __bf16 Vt[64 * 68];  // V^T[d][j], stride 68 (b64-aligned rows)

    int tid = threadIdx.x;
    int wv = tid >> 6, lane = tid & 63, quad = lane >> 4, r = lane & 15;
    int bid = blockIdx.x;
    int qt = bid % 12;
    int h = (bid / 12) % HH;
    int b = bid / (12 * HH);
    int q0 = qt * 64;
    int p0 = q0 & 255;
    const bf16* base = qkv + (size_t)b * TT * 2304;

    // Q fragments: wave wv -> queries q0 + wv*16 + r
    const bf16* qptr = base + (size_t)(q0 + wv * 16 + r) * 2304 + h * DD + quad * 8;
    bf16x8 qf0 = *(const bf16x8*)qptr;
    bf16x8 qf1 = *(const bf16x8*)(qptr + 32);

    f32x4 o[4];
#pragma unroll
    for (int z = 0; z < 4; z++) o[z] = (f32x4){0.f, 0.f, 0.f, 0.f};
    float m_i[4] = {-INFINITY, -INFINITY, -INFINITY, -INFINITY};
    float l_i[4] = {0.f, 0.f, 0.f, 0.f};

    int ntile = p0 >> 6;
    int jst = tid >> 3;            // V staging: j base
    int d8 = (tid & 7) * 8;        // V staging: d group

    for (int seg = 0; seg < 3; seg++) {
        for (int jt = 0; jt <= ntile; jt++) {
            int j0 = seg * 256 + jt * 64;
            bool diag = (jt == ntile);
            __syncthreads();   // prior tile's LDS reads done

            // stage V^T: Vt[d][j] = V[j0+j][d]
#pragma unroll
            for (int half = 0; half < 2; half++) {
                int j = jst + half * 32;
                const bf16* vp = base + (size_t)(j0 + j) * 2304 + 1536 + h * DD + d8;
                bf16x8 vv = *(const bf16x8*)vp;
#pragma unroll
                for (int u = 0; u < 8; u++) Vt[(d8 + u) * 68 + j] = vv[u];
            }

            // S = Q K^T (16x64 per wave)
            f32x4 sacc[4];
#pragma unroll
            for (int z = 0; z < 4; z++) sacc[z] = (f32x4){0.f, 0.f, 0.f, 0.f};
#pragma unroll
            for (int nt = 0; nt < 4; nt++) {
                const bf16* kp = base + (size_t)(j0 + nt * 16 + r) * 2304 + CC + h * DD + quad * 8;
                bf16x8 k0 = *(const bf16x8*)kp;
                bf16x8 k1 = *(const bf16x8*)(kp + 32);
                sacc[nt] = __builtin_amdgcn_mfma_f32_16x16x32_bf16(qf0, k0, sacc[nt], 0, 0, 0);
                sacc[nt] = __builtin_amdgcn_mfma_f32_16x16x32_bf16(qf1, k1, sacc[nt], 0, 0, 0);
            }

            // online softmax (rows = quad*4+i within wave's 16 queries)
#pragma unroll
            for (int i = 0; i < 4; i++) {
                int rowq = wv * 16 + quad * 4 + i;
                float sv[4];
                float mx = -INFINITY;
#pragma unroll
                for (int nt = 0; nt < 4; nt++) {
                    float s = sacc[nt][i] * 0.125f;
                    if (diag && (nt * 16 + r > rowq)) s = -INFINITY;
                    sv[nt] = s;
                    mx = fmaxf(mx, s);
                }
                for (int dd = 1; dd < 16; dd <<= 1) mx = fmaxf(mx, __shfl_xor(mx, dd, 64));
                float mn = fmaxf(m_i[i], mx);
                float al = __expf(m_i[i] - mn);
                float rs = 0.f;
#pragma unroll
                for (int nt = 0; nt < 4; nt++) {
                    float e = __expf(sv[nt] - mn);
                    Pl[rowq * 72 + nt * 16 + r] = (__bf16)e;
                    rs += e;
                }
                for (int dd = 1; dd < 16; dd <<= 1) rs += __shfl_xor(rs, dd, 64);
                l_i[i] = l_i[i] * al + rs;
                m_i[i] = mn;
                o[0][i] *= al; o[1][i] *= al; o[2][i] *= al; o[3][i] *= al;
            }
            __syncthreads();   // Pl, Vt visible

            // O += P V  (A = P rows, B = Vt rows)
            const __bf16* pr = Pl + (wv * 16 + r) * 72 + quad * 8;
            bf16x8 pf0 = *(const bf16x8*)pr;
            bf16x8 pf1 = *(const bf16x8*)(pr + 32);
#pragma unroll
            for (int nt = 0; nt < 4; nt++) {
                const __bf16* vr = Vt + (nt * 16 + r) * 68 + quad * 8;
                bf16x4 v0a = *(const bf16x4*)vr;
                bf16x4 v0b = *(const bf16x4*)(vr + 4);
                bf16x4 v1a = *(const bf16x4*)(vr + 32);
                bf16x4 v1b = *(const bf16x4*)(vr + 36);
                bf16x8 vf0 = __builtin_shufflevector(v0a, v0b, 0, 1, 2, 3, 4, 5, 6, 7);
                bf16x8 vf1 = __builtin_shufflevector(v1a, v1b, 0, 1, 2, 3, 4, 5, 6, 7);
                o[nt] = __builtin_amdgcn_mfma_f32_16x16x32_bf16(pf0, vf0, o[nt], 0, 0, 0);
                o[nt] = __builtin_amdgcn_mfma_f32_16x16x32_bf16(pf1, vf1, o[nt], 0, 0, 0);
            }
        }
    }

    float inv[4];
#pragma unroll
    for (int i = 0; i < 4; i++) inv[i] = 1.0f / l_i[i];
#pragma unroll
    for (int nt = 0; nt < 4; nt++)
#pragma unroll
        for (int i = 0; i < 4; i++)
            yout[(size_t)(b * TT + q0 + wv * 16 + quad * 4 + i) * CC + h * DD + nt * 16 + r]
                = f2b(o[nt][i] * inv[i]);
}

// ---------------------------------------------------------------------------
extern "C" void kernel_launch(void* const* d_in, const int* in_sizes, int n_in,
                              void* d_out, int out_size, void* d_ws, size_t ws_size,
                              hipStream_t stream)
{
    const int* idx_up     = (const int*)d_in[0];
    const int* idx_down   = (const int*)d_in[1];
    const float* cond     = (const float*)d_in[2];
    const float* tok_up   = (const float*)d_in[3];
    const float* tok_down = (const float*)d_in[4];
    const float* pos_emb  = (const float*)d_in[5];
    const float* cond_w   = (const float*)d_in[6];
    const float* cond_b   = (const float*)d_in[7];
    const float* lnf_w    = (const float*)d_in[8];
    const float* lnf_b    = (const float*)d_in[9];
    const float* head_up_w   = (const float*)d_in[10];
    const float* head_down_w = (const float*)d_in[11];
    const float* P[2][10];
    for (int s = 0; s < 2; s++)
        for (int j = 0; j < 10; j++)
            P[s][j] = (const float*)d_in[12 + s * 10 + j];

    const int Mrows = 2 * TT;  // 1536
    char* wsp = (char*)d_ws;
    float* x   = (float*)wsp;                         // fp32 [1536,768]
    bf16* bufA = (bf16*)(wsp + 4718592);              // qkv [1536,2304] / g [1536,3072]
    bf16* bufB = (bf16*)(wsp + 4718592 + 9437184);    // h / att [1536,768]
    bf16* qkv = bufA;
    bf16* g   = bufA;
    bf16* h   = bufB;
    bf16* att = bufB;
    float* outf = (float*)d_out;

    embed_kernel<<<Mrows, 256, 0, stream>>>(idx_up, idx_down, cond, tok_up,
                                            tok_down, pos_emb, cond_w, cond_b, x);

    for (int l = 0; l < 12; l++) {
        int s = l / 6, ll = l % 6;
        const float* ln1    = P[s][0] + (size_t)ll * 2 * CC;
        const float* ln2    = P[s][1] + (size_t)ll * 2 * CC;
        const float* qkv_w  = P[s][2] + (size_t)ll * 3 * CC * CC;
        const float* qkv_b  = P[s][3] + (size_t)ll * 3 * CC;
        const float* proj_w = P[s][4] + (size_t)ll * CC * CC;
        const float* proj_b = P[s][5] + (size_t)ll * CC;
        const float* fc1_w  = P[s][6] + (size_t)ll * 4 * CC * CC;
        const float* fc1_b  = P[s][7] + (size_t)ll * 4 * CC;
        const float* fc2_w  = P[s][8] + (size_t)ll * 4 * CC * CC;
        const float* fc2_b  = P[s][9] + (size_t)ll * CC;

        ln_kernel<<<Mrows, 256, 0, stream>>>(x, ln1, ln1 + CC, h);
        gemm2<GF_BIAS | GF_OUTB><<<dim3(3 * CC / 128, Mrows / 128), 256, 0, stream>>>(
            h, qkv_w, qkv_b, nullptr, qkv, Mrows, 3 * CC, CC, 0);
        attn_mfma<<<2 * HH * 12, 256, 0, stream>>>(qkv, att);
        gemm2<GF_BIAS | GF_RES><<<dim3(CC / 128, Mrows / 128), 256, 0, stream>>>(
            att, proj_w, proj_b, x, nullptr, Mrows, CC, CC, 0);
        ln_kernel<<<Mrows, 256, 0, stream>>>(x, ln2, ln2 + CC, h);
        gemm2<GF_BIAS | GF_GELU | GF_OUTB><<<dim3(FCC / 128, Mrows / 128), 256, 0, stream>>>(
            h, fc1_w, fc1_b, nullptr, g, Mrows, FCC, CC, 0);
        gemm2<GF_BIAS | GF_RES><<<dim3(CC / 128, Mrows / 128), 256, 0, stream>>>(
            g, fc2_w, fc2_b, x, nullptr, Mrows, CC, FCC, 0);
    }

    ln_kernel<<<Mrows, 256, 0, stream>>>(x, lnf_w, lnf_b, h);
    gemm2<GF_ROWMAP><<<dim3(VV / 128, 2 * Tt / 128), 256, 0, stream>>>(
        h, head_up_w, nullptr, outf, nullptr, 2 * Tt, VV, CC, 1);
    gemm2<GF_ROWMAP><<<dim3(VV / 128, 2 * Tt / 128), 256, 0, stream>>>(
        h, head_down_w, nullptr, outf + (size_t)2 * Tt * VV, nullptr, 2 * Tt, VV, CC, 2);
}

// Round 5
// 2672.452 us; speedup vs baseline: 3.4657x; 1.4662x over previous
//
#include <hip/hip_runtime.h>
#include <hip/hip_bf16.h>
#include <math.h>

// Model dims
#define Tt 256
#define TT 768      // 3*t
#define CC 768
#define HH 12
#define DD 64
#define MC 438
#define MCP 448     // padded K for cond gemm
#define VV 512
#define FCC 3072

typedef __hip_bfloat16 bf16;
typedef __bf16 bf16x4 __attribute__((ext_vector_type(4)));
typedef __bf16 bf16x8 __attribute__((ext_vector_type(8)));
typedef float f32x4 __attribute__((ext_vector_type(4)));

__device__ __forceinline__ float b2f(bf16 v) { return __bfloat162float(v); }
__device__ __forceinline__ bf16 f2b(float v) { return __float2bfloat16(v); }

// ---------------------------------------------------------------------------
// f32 -> bf16 bulk convert (n % 4 == 0), grid-stride
// ---------------------------------------------------------------------------
__global__ __launch_bounds__(256) void cvt_kernel(
    const float* __restrict__ in, __bf16* __restrict__ out, int n)
{
    int i = (blockIdx.x * 256 + threadIdx.x) * 4;
    int stride = gridDim.x * 1024;
    for (; i < n; i += stride) {
        f32x4 v = *(const f32x4*)(in + i);
        bf16x4 o;
        o[0] = (__bf16)v[0]; o[1] = (__bf16)v[1]; o[2] = (__bf16)v[2]; o[3] = (__bf16)v[3];
        *(bf16x4*)(out + i) = o;
    }
}

// f32 [rows,kin] -> bf16 [rows,kout] zero-padded
__global__ __launch_bounds__(256) void cvt_pad_kernel(
    const float* __restrict__ in, __bf16* __restrict__ out, int kin, int kout)
{
    int row = blockIdx.x;
    for (int c = threadIdx.x; c < kout; c += 256)
        out[(size_t)row * kout + c] = (c < kin) ? (__bf16)in[(size_t)row * kin + c] : (__bf16)0.f;
}

// ---------------------------------------------------------------------------
// Token gather for segments 1,2: x[b, seg*256+k, :] = tok[idx] + pos
// ---------------------------------------------------------------------------
__global__ __launch_bounds__(256) void gather_kernel(
    const int* __restrict__ idx_up, const int* __restrict__ idx_down,
    const float* __restrict__ tok_up, const float* __restrict__ tok_down,
    const float* __restrict__ pos, float* __restrict__ x)
{
    int r = blockIdx.x;            // [0,1024)
    int half = r >> 9;             // 0=up, 1=down
    int rem = r & 511;
    int b = rem >> 8, k = rem & 255;
    int time = (half + 1) * 256 + k;
    int ix = (half ? idx_down : idx_up)[b * 256 + k];
    const float* src = (half ? tok_down : tok_up) + (size_t)ix * CC;
    const float* pr = pos + (size_t)time * CC;
    float* xr = x + (size_t)(b * TT + time) * CC;
    for (int c = threadIdx.x; c < CC; c += 256)
        xr[c] = src[c] + pr[c];
}

// ---------------------------------------------------------------------------
// Fallback embed (f32 path): full embed incl. scalar cond matvec
// ---------------------------------------------------------------------------
__global__ __launch_bounds__(256) void embed_kernel(
    const int* __restrict__ idx_up, const int* __restrict__ idx_down,
    const float* __restrict__ cond, const float* __restrict__ tok_up,
    const float* __restrict__ tok_down, const float* __restrict__ pos,
    const float* __restrict__ cond_w, const float* __restrict__ cond_b,
    float* __restrict__ x)
{
    int row = blockIdx.x;
    int b = row / TT, i = row - b * TT;
    int tid = threadIdx.x;
    for (int c = tid; c < CC; c += 256) {
        float v;
        if (i < Tt) {
            const float* crow = cond + (size_t)(b * Tt + i) * MC;
            const float* wrow = cond_w + (size_t)c * MC;
            float acc = 0.f;
            for (int m = 0; m < MC; m++) acc += crow[m] * wrow[m];
            v = acc + cond_b[c];
        } else if (i < 2 * Tt) {
            int ix = idx_up[b * Tt + (i - Tt)];
            v = tok_up[(size_t)ix * CC + c];
        } else {
            int ix = idx_down[b * Tt + (i - 2 * Tt)];
            v = tok_down[(size_t)ix * CC + c];
        }
        x[(size_t)row * CC + c] = v + pos[(size_t)i * CC + c];
    }
}

// ---------------------------------------------------------------------------
// LayerNorm over C=768: fp32 in, bf16 out.
// ---------------------------------------------------------------------------
__global__ __launch_bounds__(256) void ln_kernel(
    const float* __restrict__ x, const float* __restrict__ w,
    const float* __restrict__ b, bf16* __restrict__ out)
{
    __shared__ float red[256];
    int row = blockIdx.x, tid = threadIdx.x;
    const float* xr = x + (size_t)row * CC;
    float v0 = xr[tid], v1 = xr[tid + 256], v2 = xr[tid + 512];
    red[tid] = v0 + v1 + v2;
    __syncthreads();
    for (int st = 128; st > 0; st >>= 1) {
        if (tid < st) red[tid] += red[tid + st];
        __syncthreads();
    }
    float mu = red[0] * (1.0f / 768.0f);
    __syncthreads();
    float d0 = v0 - mu, d1 = v1 - mu, d2 = v2 - mu;
    red[tid] = d0 * d0 + d1 * d1 + d2 * d2;
    __syncthreads();
    for (int st = 128; st > 0; st >>= 1) {
        if (tid < st) red[tid] += red[tid + st];
        __syncthreads();
    }
    float rstd = rsqrtf(red[0] * (1.0f / 768.0f) + 1e-5f);
    bf16* orow = out + (size_t)row * CC;
    orow[tid]       = f2b(d0 * rstd * w[tid]       + b[tid]);
    orow[tid + 256] = f2b(d1 * rstd * w[tid + 256] + b[tid + 256]);
    orow[tid + 512] = f2b(d2 * rstd * w[tid + 512] + b[tid + 512]);
}

// ---------------------------------------------------------------------------
// GEMM 128x128 tile, LDS-staged + register-prefetch pipeline.
// A bf16 [M,K]; W bf16 (WB=true) or f32-with-cvt (WB=false), [N,K].
// 256 thr = 4 waves (2x2 of 64x64); BK=32.
// ---------------------------------------------------------------------------
#define GF_BIAS 1
#define GF_GELU 2
#define GF_RES  4
#define GF_OUTB 8
#define GF_ROWMAP 16
#define GF_EMB 32

template <int F, bool WB>
__global__ __launch_bounds__(256) void gemm2(
    const bf16* __restrict__ A, const void* __restrict__ Wv,
    const float* __restrict__ bias, float* __restrict__ outf,
    bf16* __restrict__ outb, const float* __restrict__ pos,
    int M, int N, int K, int seg)
{
    __shared__ __align__(16) __bf16 As[128 * 32];   // row stride 32
    __shared__ __align__(16) __bf16 Ws[128 * 40];   // row stride 40 (bank spread)

    int tid = threadIdx.x;
    int wv = tid >> 6, lane = tid & 63, quad = lane >> 4, r = lane & 15;
    int m0 = blockIdx.y * 128, n0 = blockIdx.x * 128;
    int mw = (wv & 1) * 64, nw = (wv >> 1) * 64;

    // staging slots: 512 of 8 elems; slot -> row=slot>>2, col=(slot&3)*8
    int s0 = tid, s1 = tid + 256;
    int ar0 = s0 >> 2, ac0 = (s0 & 3) * 8;
    int ar1 = s1 >> 2, ac1 = (s1 & 3) * 8;
    int am0 = m0 + ar0, am1 = m0 + ar1;
    if (F & GF_ROWMAP) {
        am0 = (am0 >> 8) * TT + seg * Tt + (am0 & 255);
        am1 = (am1 >> 8) * TT + seg * Tt + (am1 & 255);
    }
    const bf16* ap0 = A + (size_t)am0 * K + ac0;
    const bf16* ap1 = A + (size_t)am1 * K + ac1;
    const __bf16* wbp = (const __bf16*)Wv;
    const float*  wfp = (const float*)Wv;
    size_t wo0 = (size_t)(n0 + ar0) * K + ac0;
    size_t wo1 = (size_t)(n0 + ar1) * K + ac1;

    f32x4 acc[16];
#pragma unroll
    for (int z = 0; z < 16; z++) acc[z] = (f32x4){0.f, 0.f, 0.f, 0.f};

    // prefetch k=0
    bf16x8 aR0 = *(const bf16x8*)ap0;
    bf16x8 aR1 = *(const bf16x8*)ap1;
    bf16x8 wR0, wR1;
    if (WB) {
        wR0 = *(const bf16x8*)(wbp + wo0);
        wR1 = *(const bf16x8*)(wbp + wo1);
    } else {
        f32x4 q0 = *(const f32x4*)(wfp + wo0), q1 = *(const f32x4*)(wfp + wo0 + 4);
        f32x4 q2 = *(const f32x4*)(wfp + wo1), q3 = *(const f32x4*)(wfp + wo1 + 4);
        wR0[0]=(__bf16)q0[0]; wR0[1]=(__bf16)q0[1]; wR0[2]=(__bf16)q0[2]; wR0[3]=(__bf16)q0[3];
        wR0[4]=(__bf16)q1[0]; wR0[5]=(__bf16)q1[1]; wR0[6]=(__bf16)q1[2]; wR0[7]=(__bf16)q1[3];
        wR1[0]=(__bf16)q2[0]; wR1[1]=(__bf16)q2[1]; wR1[2]=(__bf16)q2[2]; wR1[3]=(__bf16)q2[3];
        wR1[4]=(__bf16)q3[0]; wR1[5]=(__bf16)q3[1]; wR1[6]=(__bf16)q3[2]; wR1[7]=(__bf16)q3[3];
    }

    for (int k0 = 0; k0 < K; k0 += 32) {
        if (k0) __syncthreads();          // prior tile reads done
        *(bf16x8*)(As + s0 * 8) = aR0;
        *(bf16x8*)(As + s1 * 8) = aR1;
        *(bf16x8*)(Ws + ar0 * 40 + ac0) = wR0;
        *(bf16x8*)(Ws + ar1 * 40 + ac1) = wR1;
        __syncthreads();

        int kn = k0 + 32;
        if (kn < K) {                      // prefetch next chunk (flies over MFMA)
            aR0 = *(const bf16x8*)(ap0 + kn);
            aR1 = *(const bf16x8*)(ap1 + kn);
            if (WB) {
                wR0 = *(const bf16x8*)(wbp + wo0 + kn);
                wR1 = *(const bf16x8*)(wbp + wo1 + kn);
            } else {
                f32x4 q0 = *(const f32x4*)(wfp + wo0 + kn), q1 = *(const f32x4*)(wfp + wo0 + kn + 4);
                f32x4 q2 = *(const f32x4*)(wfp + wo1 + kn), q3 = *(const f32x4*)(wfp + wo1 + kn + 4);
                wR0[0]=(__bf16)q0[0]; wR0[1]=(__bf16)q0[1]; wR0[2]=(__bf16)q0[2]; wR0[3]=(__bf16)q0[3];
                wR0[4]=(__bf16)q1[0]; wR0[5]=(__bf16)q1[1]; wR0[6]=(__bf16)q1[2]; wR0[7]=(__bf16)q1[3];
                wR1[0]=(__bf16)q2[0]; wR1[1]=(__bf16)q2[1]; wR1[2]=(__bf16)q2[2]; wR1[3]=(__bf16)q2[3];
                wR1[4]=(__bf16)q3[0]; wR1[5]=(__bf16)q3[1]; wR1[6]=(__bf16)q3[2]; wR1[7]=(__bf16)q3[3];
            }
        }

        bf16x8 af[4], bfr[4];
#pragma unroll
        for (int mi = 0; mi < 4; mi++)
            af[mi] = *(const bf16x8*)(As + (mw + mi * 16 + r) * 32 + quad * 8);
#pragma unroll
        for (int ni = 0; ni < 4; ni++)
            bfr[ni] = *(const bf16x8*)(Ws + (nw + ni * 16 + r) * 40 + quad * 8);
#pragma unroll
        for (int mi = 0; mi < 4; mi++)
#pragma unroll
            for (int ni = 0; ni < 4; ni++)
                acc[mi * 4 + ni] = __builtin_amdgcn_mfma_f32_16x16x32_bf16(
                    af[mi], bfr[ni], acc[mi * 4 + ni], 0, 0, 0);
    }

#pragma unroll
    for (int mi = 0; mi < 4; mi++) {
        int row = m0 + mw + mi * 16 + quad * 4;
#pragma unroll
        for (int ni = 0; ni < 4; ni++) {
            int col = n0 + nw + ni * 16 + r;
            float bv = (F & GF_BIAS) ? bias[col] : 0.f;
            f32x4 v4 = acc[mi * 4 + ni];
#pragma unroll
            for (int i = 0; i < 4; i++) {
                float v = v4[i] + bv;
                if (F & GF_GELU) v = 0.5f * v * (1.0f + erff(v * 0.70710678118654752f));
                size_t oi;
                if (F & GF_EMB) {
                    int rr = row + i;
                    int ti = rr & 255;
                    oi = (size_t)((rr >> 8) * TT + ti) * N + col;
                    v += pos[(size_t)ti * N + col];
                } else {
                    oi = (size_t)(row + i) * N + col;
                }
                if (F & GF_RES) v += outf[oi];
                if (F & GF_OUTB) outb[oi] = f2b(v);
                else             outf[oi] = v;
            }
        }
    }
}

// ---------------------------------------------------------------------------
// Flash attention, MFMA. Block = (b, h, 64-query tile); 4 waves x 16 queries.
// ---------------------------------------------------------------------------
__global__ __launch_bounds__(256) void attn_mfma(
    const bf16* __restrict__ qkv, bf16* __restrict__ yout)
{
    __shared__ __align__(16) __bf16 Pl[64 * 72];
    __shared__ __align__(16) __bf16 Vt[64 * 68];

    int tid = threadIdx.x;
    int wv = tid >> 6, lane = tid & 63, quad = lane >> 4, r = lane & 15;
    int bid = blockIdx.x;
    int qt = bid % 12;
    int h = (bid / 12) % HH;
    int b = bid / (12 * HH);
    int q0 = qt * 64;
    int p0 = q0 & 255;
    const bf16* base = qkv + (size_t)b * TT * 2304;

    const bf16* qptr = base + (size_t)(q0 + wv * 16 + r) * 2304 + h * DD + quad * 8;
    bf16x8 qf0 = *(const bf16x8*)qptr;
    bf16x8 qf1 = *(const bf16x8*)(qptr + 32);

    f32x4 o[4];
#pragma unroll
    for (int z = 0; z < 4; z++) o[z] = (f32x4){0.f, 0.f, 0.f, 0.f};
    float m_i[4] = {-INFINITY, -INFINITY, -INFINITY, -INFINITY};
    float l_i[4] = {0.f, 0.f, 0.f, 0.f};

    int ntile = p0 >> 6;
    int jst = tid >> 3;
    int d8 = (tid & 7) * 8;

    for (int seg = 0; seg < 3; seg++) {
        for (int jt = 0; jt <= ntile; jt++) {
            int j0 = seg * 256 + jt * 64;
            bool diag = (jt == ntile);
            __syncthreads();

#pragma unroll
            for (int half = 0; half < 2; half++) {
                int j = jst + half * 32;
                const bf16* vp = base + (size_t)(j0 + j) * 2304 + 1536 + h * DD + d8;
                bf16x8 vv = *(const bf16x8*)vp;
#pragma unroll
                for (int u = 0; u < 8; u++) Vt[(d8 + u) * 68 + j] = vv[u];
            }

            f32x4 sacc[4];
#pragma unroll
            for (int z = 0; z < 4; z++) sacc[z] = (f32x4){0.f, 0.f, 0.f, 0.f};
#pragma unroll
            for (int nt = 0; nt < 4; nt++) {
                const bf16* kp = base + (size_t)(j0 + nt * 16 + r) * 2304 + CC + h * DD + quad * 8;
                bf16x8 k0 = *(const bf16x8*)kp;
                bf16x8 k1 = *(const bf16x8*)(kp + 32);
                sacc[nt] = __builtin_amdgcn_mfma_f32_16x16x32_bf16(qf0, k0, sacc[nt], 0, 0, 0);
                sacc[nt] = __builtin_amdgcn_mfma_f32_16x16x32_bf16(qf1, k1, sacc[nt], 0, 0, 0);
            }

#pragma unroll
            for (int i = 0; i < 4; i++) {
                int rowq = wv * 16 + quad * 4 + i;
                float sv[4];
                float mx = -INFINITY;
#pragma unroll
                for (int nt = 0; nt < 4; nt++) {
                    float s = sacc[nt][i] * 0.125f;
                    if (diag && (nt * 16 + r > rowq)) s = -INFINITY;
                    sv[nt] = s;
                    mx = fmaxf(mx, s);
                }
                for (int dd = 1; dd < 16; dd <<= 1) mx = fmaxf(mx, __shfl_xor(mx, dd, 64));
                float mn = fmaxf(m_i[i], mx);
                float al = __expf(m_i[i] - mn);
                float rs = 0.f;
#pragma unroll
                for (int nt = 0; nt < 4; nt++) {
                    float e = __expf(sv[nt] - mn);
                    Pl[rowq * 72 + nt * 16 + r] = (__bf16)e;
                    rs += e;
                }
                for (int dd = 1; dd < 16; dd <<= 1) rs += __shfl_xor(rs, dd, 64);
                l_i[i] = l_i[i] * al + rs;
                m_i[i] = mn;
                o[0][i] *= al; o[1][i] *= al; o[2][i] *= al; o[3][i] *= al;
            }
            __syncthreads();

            const __bf16* pr = Pl + (wv * 16 + r) * 72 + quad * 8;
            bf16x8 pf0 = *(const bf16x8*)pr;
            bf16x8 pf1 = *(const bf16x8*)(pr + 32);
#pragma unroll
            for (int nt = 0; nt < 4; nt++) {
                const __bf16* vr = Vt + (nt * 16 + r) * 68 + quad * 8;
                bf16x4 v0a = *(const bf16x4*)vr;
                bf16x4 v0b = *(const bf16x4*)(vr + 4);
                bf16x4 v1a = *(const bf16x4*)(vr + 32);
                bf16x4 v1b = *(const bf16x4*)(vr + 36);
                bf16x8 vf0 = __builtin_shufflevector(v0a, v0b, 0, 1, 2, 3, 4, 5, 6, 7);
                bf16x8 vf1 = __builtin_shufflevector(v1a, v1b, 0, 1, 2, 3, 4, 5, 6, 7);
                o[nt] = __builtin_amdgcn_mfma_f32_16x16x32_bf16(pf0, vf0, o[nt], 0, 0, 0);
                o[nt] = __builtin_amdgcn_mfma_f32_16x16x32_bf16(pf1, vf1, o[nt], 0, 0, 0);
            }
        }
    }

    float inv[4];
#pragma unroll
    for (int i = 0; i < 4; i++) inv[i] = 1.0f / l_i[i];
#pragma unroll
    for (int nt = 0; nt < 4; nt++)
#pragma unroll
        for (int i = 0; i < 4; i++)
            yout[(size_t)(b * TT + q0 + wv * 16 + quad * 4 + i) * CC + h * DD + nt * 16 + r]
                = f2b(o[nt][i] * inv[i]);
}

// ---------------------------------------------------------------------------
extern "C" void kernel_launch(void* const* d_in, const int* in_sizes, int n_in,
                              void* d_out, int out_size, void* d_ws, size_t ws_size,
                              hipStream_t stream)
{
    const int* idx_up     = (const int*)d_in[0];
    const int* idx_down   = (const int*)d_in[1];
    const float* cond     = (const float*)d_in[2];
    const float* tok_up   = (const float*)d_in[3];
    const float* tok_down = (const float*)d_in[4];
    const float* pos_emb  = (const float*)d_in[5];
    const float* cond_w   = (const float*)d_in[6];
    const float* cond_b   = (const float*)d_in[7];
    const float* lnf_w    = (const float*)d_in[8];
    const float* lnf_b    = (const float*)d_in[9];
    const float* head_up_w   = (const float*)d_in[10];
    const float* head_down_w = (const float*)d_in[11];
    const float* P[2][10];
    for (int s = 0; s < 2; s++)
        for (int j = 0; j < 10; j++)
            P[s][j] = (const float*)d_in[12 + s * 10 + j];

    const int Mrows = 2 * TT;  // 1536
    char* wsp = (char*)d_ws;
    float* x   = (float*)wsp;                         // fp32 [1536,768]
    bf16* bufA = (bf16*)(wsp + 4718592);              // qkv / g
    bf16* bufB = (bf16*)(wsp + 4718592 + 9437184);    // h / att
    bf16* qkv = bufA;
    bf16* g   = bufA;
    bf16* h   = bufB;
    bf16* att = bufB;
    float* outf = (float*)d_out;

    // bf16 weight cache layout (big path)
    size_t off = 16515072;
    __bf16* condC = (__bf16*)(wsp + off); off += 458752;     // [512,448]
    __bf16* condW = (__bf16*)(wsp + off); off += 688128;     // [768,448]
    __bf16* headU = (__bf16*)(wsp + off); off += 786432;     // [512,768]
    __bf16* headD = (__bf16*)(wsp + off); off += 786432;
    __bf16 *wQ[2], *wP[2], *wF1[2], *wF2[2];
    for (int s = 0; s < 2; s++) {
        wQ[s]  = (__bf16*)(wsp + off); off += 21233664;      // [6,3*768,768]
        wP[s]  = (__bf16*)(wsp + off); off += 7077888;       // [6,768,768]
        wF1[s] = (__bf16*)(wsp + off); off += 28311552;      // [6,3072,768]
        wF2[s] = (__bf16*)(wsp + off); off += 28311552;      // [6,768,3072]
    }
    bool big = (ws_size >= off);

    if (big) {
        cvt_pad_kernel<<<512, 256, 0, stream>>>(cond, condC, MC, MCP);
        cvt_pad_kernel<<<768, 256, 0, stream>>>(cond_w, condW, MC, MCP);
        cvt_kernel<<<384, 256, 0, stream>>>(head_up_w, headU, VV * CC);
        cvt_kernel<<<384, 256, 0, stream>>>(head_down_w, headD, VV * CC);
        for (int s = 0; s < 2; s++) {
            cvt_kernel<<<4096, 256, 0, stream>>>(P[s][2], wQ[s], 6 * 3 * CC * CC);
            cvt_kernel<<<3456, 256, 0, stream>>>(P[s][4], wP[s], 6 * CC * CC);
            cvt_kernel<<<4096, 256, 0, stream>>>(P[s][6], wF1[s], 6 * FCC * CC);
            cvt_kernel<<<4096, 256, 0, stream>>>(P[s][8], wF2[s], 6 * CC * FCC);
        }
        // embed: cond GEMM (M=512,N=768,K=448) + gather for token segments
        gemm2<GF_BIAS | GF_EMB, true><<<dim3(6, 4), 256, 0, stream>>>(
            (const bf16*)condC, condW, cond_b, x, nullptr, pos_emb, 512, CC, MCP, 0);
        gather_kernel<<<1024, 256, 0, stream>>>(idx_up, idx_down, tok_up, tok_down, pos_emb, x);
    } else {
        embed_kernel<<<Mrows, 256, 0, stream>>>(idx_up, idx_down, cond, tok_up,
                                                tok_down, pos_emb, cond_w, cond_b, x);
    }

    for (int l = 0; l < 12; l++) {
        int s = l / 6, ll = l % 6;
        const float* ln1    = P[s][0] + (size_t)ll * 2 * CC;
        const float* ln2    = P[s][1] + (size_t)ll * 2 * CC;
        const float* qkv_b  = P[s][3] + (size_t)ll * 3 * CC;
        const float* proj_b = P[s][5] + (size_t)ll * CC;
        const float* fc1_b  = P[s][7] + (size_t)ll * 4 * CC;
        const float* fc2_b  = P[s][9] + (size_t)ll * CC;

        const void* qkv_w  = big ? (const void*)(wQ[s]  + (size_t)ll * 3 * CC * CC)
                                 : (const void*)(P[s][2] + (size_t)ll * 3 * CC * CC);
        const void* proj_w = big ? (const void*)(wP[s]  + (size_t)ll * CC * CC)
                                 : (const void*)(P[s][4] + (size_t)ll * CC * CC);
        const void* fc1_w  = big ? (const void*)(wF1[s] + (size_t)ll * 4 * CC * CC)
                                 : (const void*)(P[s][6] + (size_t)ll * 4 * CC * CC);
        const void* fc2_w  = big ? (const void*)(wF2[s] + (size_t)ll * 4 * CC * CC)
                                 : (const void*)(P[s][8] + (size_t)ll * 4 * CC * CC);

        ln_kernel<<<Mrows, 256, 0, stream>>>(x, ln1, ln1 + CC, h);
        if (big) {
            gemm2<GF_BIAS | GF_OUTB, true><<<dim3(3 * CC / 128, Mrows / 128), 256, 0, stream>>>(
                h, qkv_w, qkv_b, nullptr, qkv, nullptr, Mrows, 3 * CC, CC, 0);
        } else {
            gemm2<GF_BIAS | GF_OUTB, false><<<dim3(3 * CC / 128, Mrows / 128), 256, 0, stream>>>(
                h, qkv_w, qkv_b, nullptr, qkv, nullptr, Mrows, 3 * CC, CC, 0);
        }
        attn_mfma<<<2 * HH * 12, 256, 0, stream>>>(qkv, att);
        if (big) {
            gemm2<GF_BIAS | GF_RES, true><<<dim3(CC / 128, Mrows / 128), 256, 0, stream>>>(
                att, proj_w, proj_b, x, nullptr, nullptr, Mrows, CC, CC, 0);
        } else {
            gemm2<GF_BIAS | GF_RES, false><<<dim3(CC / 128, Mrows / 128), 256, 0, stream>>>(
                att, proj_w, proj_b, x, nullptr, nullptr, Mrows, CC, CC, 0);
        }
        ln_kernel<<<Mrows, 256, 0, stream>>>(x, ln2, ln2 + CC, h);
        if (big) {
            gemm2<GF_BIAS | GF_GELU | GF_OUTB, true><<<dim3(FCC / 128, Mrows / 128), 256, 0, stream>>>(
                h, fc1_w, fc1_b, nullptr, g, nullptr, Mrows, FCC, CC, 0);
            gemm2<GF_BIAS | GF_RES, true><<<dim3(CC / 128, Mrows / 128), 256, 0, stream>>>(
                g, fc2_w, fc2_b, x, nullptr, nullptr, Mrows, CC, FCC, 0);
        } else {
            gemm2<GF_BIAS | GF_GELU | GF_OUTB, false><<<dim3(FCC / 128, Mrows / 128), 256, 0, stream>>>(
                h, fc1_w, fc1_b, nullptr, g, nullptr, Mrows, FCC, CC, 0);
            gemm2<GF_BIAS | GF_RES, false><<<dim3(CC / 128, Mrows / 128), 256, 0, stream>>>(
                g, fc2_w, fc2_b, x, nullptr, nullptr, Mrows, CC, FCC, 0);
        }
    }

    ln_kernel<<<Mrows, 256, 0, stream>>>(x, lnf_w, lnf_b, h);
    if (big) {
        gemm2<GF_ROWMAP, true><<<dim3(VV / 128, 2 * Tt / 128), 256, 0, stream>>>(
            h, headU, nullptr, outf, nullptr, nullptr, 2 * Tt, VV, CC, 1);
        gemm2<GF_ROWMAP, true><<<dim3(VV / 128, 2 * Tt / 128), 256, 0, stream>>>(
            h, headD, nullptr, outf + (size_t)2 * Tt * VV, nullptr, nullptr, 2 * Tt, VV, CC, 2);
    } else {
        gemm2<GF_ROWMAP, false><<<dim3(VV / 128, 2 * Tt / 128), 256, 0, stream>>>(
            h, head_up_w, nullptr, outf, nullptr, nullptr, 2 * Tt, VV, CC, 1);
        gemm2<GF_ROWMAP, false><<<dim3(VV / 128, 2 * Tt / 128), 256, 0, stream>>>(
            h, head_down_w, nullptr, outf + (size_t)2 * Tt * VV, nullptr, nullptr, 2 * Tt, VV, CC, 2);
    }
}